// Round 2
// baseline (315.964 us; speedup 1.0000x reference)
//
#include <hip/hip_runtime.h>
#include <hip/hip_bf16.h>

typedef __attribute__((ext_vector_type(8))) short short8;
typedef __attribute__((ext_vector_type(4))) float floatx4;

__device__ __forceinline__ float sigm(float x) { return 1.0f / (1.0f + __expf(-x)); }

__device__ __forceinline__ unsigned short f2bf(float v) {
  union { __hip_bfloat16 h; unsigned short u; } cv;
  cv.h = __float2bfloat16(v);
  return cv.u;
}

// ---------------- B fragment-order layout ----------------
// Weights are pre-swizzled into exact MFMA B-fragment order so the main loop
// loads each fragment as ONE coalesced global_load_dwordx4 (64 lanes x 16B = 1KB).
// Element (n, k), n in 0..175, k in 0..C-1:
//   nj=n>>4, l15=n&15, it=k>>6, kk=k&63, h=kk>>5, quad=(kk>>3)&3, j=kk&7
//   lane = quad*16+l15; ushort index = ((it*11+nj)*2+h)*512 + lane*8 + j
// Main-loop read: lane's short8 at byte off  it*22528 + nj*2048 + h*1024 + lane*16
// gives B[n=l15][k=it*64 + h*32 + quad*8 + j]  == verified 16x16x32 B-frag mapping.
__device__ __forceinline__ size_t boff(int n, int k) {
  const int nj = n >> 4, l15 = n & 15;
  const int it = k >> 6, kk = k & 63;
  const int h = kk >> 5, quad = (kk >> 3) & 3, j = kk & 7;
  return ((size_t)((it * 11 + nj) * 2 + h) * 512) + (size_t)(quad * 16 + l15) * 8 + j;
}

// ---------------- prep: fold ia/im/bias into fragment-ordered bf16 weights ----------------
// Combined channel n (0..170): n<18 -> det row n (scaled by im, bias im*(b + W.ia));
//                              n>=18 -> kpt row n-18 (bias bk). Rows 171..175 zero.
struct PrepArgs {
  const float *w, *b, *im, *ia, *wk, *bk;
  unsigned short* Wp;
  float* bias;
  int C;
};

__global__ void prep_kernel(PrepArgs A0, PrepArgs A1, PrepArgs A2) {
  PrepArgs A = (blockIdx.y == 0) ? A0 : (blockIdx.y == 1) ? A1 : A2;
  const int n = blockIdx.x;   // 0..175
  const int t = threadIdx.x;  // 0..63
  const int C = A.C;
  if (n >= 171) {
    for (int k = t; k < C; k += 64) A.Wp[boff(n, k)] = 0;
    if (t == 0) A.bias[n] = 0.0f;
    return;
  }
  if (n < 18) {
    const float* src = A.w + (size_t)n * C;
    const float sc = A.im[n];
    float dot = 0.0f;
    for (int k = t; k < C; k += 64) {
      float v = src[k];
      dot += v * A.ia[k];
      A.Wp[boff(n, k)] = f2bf(v * sc);
    }
#pragma unroll
    for (int off = 32; off > 0; off >>= 1) dot += __shfl_down(dot, off);
    if (t == 0) A.bias[n] = sc * (A.b[n] + dot);
  } else {
    const float* src = A.wk + (size_t)(n - 18) * C;
    for (int k = t; k < C; k += 64) A.Wp[boff(n, k)] = f2bf(src[k]);
    if (t == 0) A.bias[n] = A.bk[n - 18];
  }
}

// ---------------- barrier-free fused GEMM (bf16 MFMA) + decode ----------------
// Block = 64 m x 176 n, 4 waves; each wave owns 16 m rows, fully independent.
// A: fp32 direct global->fragment-register gathers, prefetched 1 iter ahead.
// B: L2-resident, loaded straight into fragment registers (pre-swizzled layout,
//    1KB-coalesced dwordx4 per fragment). NO LDS / NO barriers / NO asm waits in
//    the K-loop -- all s_waitcnt are compiler-derived, waves never convoy.
#define LDS_BYTES 23040  // epilogue only: [32][180] fp32

template <int SC, int C, int HW, int W>
__device__ __forceinline__ void gemm_decode(const float* __restrict__ feat,
                                            const unsigned short* __restrict__ Wp,
                                            const float* __restrict__ bias,
                                            float* __restrict__ out, int tile, char* smem) {
  constexpr float STRD = (SC == 0) ? 8.0f : (SC == 1) ? 16.0f : 32.0f;
  constexpr int ZOFF = (SC == 0) ? 0 : (SC == 1) ? 19200 : 24000;
  constexpr int I = C / 64;

  const int t = threadIdx.x;
  const int lane = t & 63;
  const int wv = t >> 6;
  const int l15 = lane & 15;
  const int quad = lane >> 4;

  float* Elds = (float*)smem;  // epilogue [32][180] fp32

  // ---- A: direct-to-fragment gather mapping ----
  // fragment layout (16x16x32): lane holds A[row=l15][k=quad*8+j] (af0), +32 (af1)
  const int mA = tile * 64 + wv * 16 + l15;
  const int bA = mA / HW;
  const int pA = mA - bA * HW;
  const float* fbase = feat + ((size_t)bA * C + quad * 8) * (size_t)HW + pA;

  // ---- B: fragment-ordered base (per-lane 16B slot) ----
  const char* Bbase = (const char*)Wp + lane * 16;

  floatx4 acc[11];
#pragma unroll
  for (int nj = 0; nj < 11; ++nj) acc[nj] = (floatx4){0.f, 0.f, 0.f, 0.f};

  float v[16];
  auto loadA = [&](int it) {
    const float* g = fbase + (size_t)it * 64 * HW;
#pragma unroll
    for (int j = 0; j < 8; ++j) {
      v[j] = g[(size_t)j * HW];
      v[j + 8] = g[(size_t)(32 + j) * HW];
    }
  };

  loadA(0);
#pragma unroll 1
  for (int it = 0; it < I; ++it) {
    // convert A(it) -> bf16 fragments (compiler waits only the 16 A loads,
    // which were issued a full iteration ago)
    short8 af0, af1;
#pragma unroll
    for (int j = 0; j < 8; ++j) {
      af0[j] = (short)f2bf(v[j]);
      af1[j] = (short)f2bf(v[j + 8]);
    }
    // prefetch next A tile; issued before the B/MFMA cluster so its latency is
    // covered by the MFMA phase (and at worst absorbed by the last B-wait)
    if (it + 1 < I) loadA(it + 1);
    __builtin_amdgcn_sched_barrier(0);
    // B fragments straight from L2 into registers; compiler pipelines the
    // unrolled nj-loop (loads hoisted ahead of consuming MFMAs as regs allow)
    const char* bp = Bbase + (size_t)it * 22528;
#pragma unroll
    for (int nj = 0; nj < 11; ++nj) {
      short8 b0 = *(const short8*)(bp + nj * 2048);
      short8 b1 = *(const short8*)(bp + nj * 2048 + 1024);
      acc[nj] = __builtin_amdgcn_mfma_f32_16x16x32_bf16(af0, b0, acc[nj], 0, 0, 0);
      acc[nj] = __builtin_amdgcn_mfma_f32_16x16x32_bf16(af1, b1, acc[nj], 0, 0, 0);
    }
  }

  // ---------------- epilogue: 2 chunks of 32 rows ----------------
  float bj[11];
#pragma unroll
  for (int nj = 0; nj < 11; ++nj) bj[nj] = bias[nj * 16 + l15];

#pragma unroll
  for (int c = 0; c < 2; ++c) {
    __syncthreads();
    if ((wv >> 1) == c) {
      const int rbase = (wv & 1) * 16 + quad * 4;
#pragma unroll
      for (int nj = 0; nj < 11; ++nj)
#pragma unroll
        for (int r = 0; r < 4; ++r)
          Elds[(rbase + r) * 180 + nj * 16 + l15] = acc[nj][r] + bj[nj];
    }
    __syncthreads();
    if (t < 192) {
      const int task = t >> 1, half = t & 1;
      const int row = task & 31, a = task >> 5;
      const int m = tile * 64 + c * 32 + row;
      const int bb = m / HW;
      const int p = m - bb * HW;
      const float fx = (float)(p % W);
      const float fy = (float)(p / W);
      float* L = Elds + row * 180 + a * 57;
      if (half == 0) {
        float aw, ah;
        if constexpr (SC == 0) {
          aw = (a == 0) ? 19.f : (a == 1) ? 44.f : 38.f;
          ah = (a == 0) ? 27.f : (a == 1) ? 40.f : 94.f;
        } else if constexpr (SC == 1) {
          aw = (a == 0) ? 96.f : (a == 1) ? 86.f : 180.f;
          ah = (a == 0) ? 68.f : (a == 1) ? 152.f : 137.f;
        } else {
          aw = (a == 0) ? 140.f : (a == 1) ? 303.f : 238.f;
          ah = (a == 0) ? 301.f : (a == 1) ? 264.f : 542.f;
        }
        float r0 = L[0], r1 = L[1], r2 = L[2], r3 = L[3], r4 = L[4], r5 = L[5];
        L[0] = (sigm(r0) * 2.f - 0.5f + fx) * STRD;
        L[1] = (sigm(r1) * 2.f - 0.5f + fy) * STRD;
        float tw = sigm(r2) * 2.f;
        L[2] = tw * tw * aw;
        float th = sigm(r3) * 2.f;
        L[3] = th * th * ah;
        L[4] = sigm(r4);
        L[5] = sigm(r5);
#pragma unroll
        for (int kp = 0; kp < 8; ++kp) {
          float kx = L[6 + 3 * kp], ky = L[7 + 3 * kp], kc = L[8 + 3 * kp];
          L[6 + 3 * kp] = (kx * 2.f - 0.5f + fx) * STRD;
          L[7 + 3 * kp] = (ky * 2.f - 0.5f + fy) * STRD;
          L[8 + 3 * kp] = sigm(kc);
        }
      } else {
#pragma unroll
        for (int kp = 8; kp < 17; ++kp) {
          float kx = L[6 + 3 * kp], ky = L[7 + 3 * kp], kc = L[8 + 3 * kp];
          L[6 + 3 * kp] = (kx * 2.f - 0.5f + fx) * STRD;
          L[7 + 3 * kp] = (ky * 2.f - 0.5f + fy) * STRD;
          L[8 + 3 * kp] = sigm(kc);
        }
      }
    }
    __syncthreads();
    for (int i = t; i < 96 * 57; i += 256) {
      int sr = i / 57;
      int j = i - sr * 57;
      int a = sr >> 5, row = sr & 31;
      int m = tile * 64 + c * 32 + row;
      int bb = m / HW;
      int p = m - bb * HW;
      out[((size_t)bb * 25200 + (size_t)(ZOFF + a * HW + p)) * 57 + j] =
          Elds[row * 180 + a * 57 + j];
    }
  }
}

__global__ __launch_bounds__(256, 4) void main_kernel(
    const float* __restrict__ f0, const float* __restrict__ f1, const float* __restrict__ f2,
    const unsigned short* __restrict__ Wp0, const unsigned short* __restrict__ Wp1,
    const unsigned short* __restrict__ Wp2, const float* __restrict__ b0,
    const float* __restrict__ b1, const float* __restrict__ b2, float* __restrict__ out) {
  __shared__ __align__(16) char smem[LDS_BYTES];
  const int bid = blockIdx.x;
  // longest blocks (scale 2, C=1024) first to amortize the tail
  if (bid < 100)
    gemm_decode<2, 1024, 400, 20>(f2, Wp2, b2, out, bid, smem);
  else if (bid < 500)
    gemm_decode<1, 512, 1600, 40>(f1, Wp1, b1, out, bid - 100, smem);
  else
    gemm_decode<0, 256, 6400, 80>(f0, Wp0, b0, out, bid - 500, smem);
}

extern "C" void kernel_launch(void* const* d_in, const int* in_sizes, int n_in, void* d_out,
                              int out_size, void* d_ws, size_t ws_size, hipStream_t stream) {
  const float *f[3], *ia[3], *w[3], *b[3], *im[3], *wk[3], *bk[3];
  for (int s = 0; s < 3; ++s) {
    f[s] = (const float*)d_in[7 * s + 0];
    ia[s] = (const float*)d_in[7 * s + 1];
    w[s] = (const float*)d_in[7 * s + 2];
    b[s] = (const float*)d_in[7 * s + 3];
    im[s] = (const float*)d_in[7 * s + 4];
    wk[s] = (const float*)d_in[7 * s + 5];
    bk[s] = (const float*)d_in[7 * s + 6];
  }
  // workspace: fragment-ordered Wp[s]: C*352 bytes each
  // Wp0 @0 (90112B) | Wp1 @98304 (180224B) | Wp2 @294912 (360448B) | 3x bias f32
  char* ws = (char*)d_ws;
  unsigned short* Wp0 = (unsigned short*)(ws + 0);
  unsigned short* Wp1 = (unsigned short*)(ws + 98304);
  unsigned short* Wp2 = (unsigned short*)(ws + 294912);
  float* bias0 = (float*)(ws + 688128);
  float* bias1 = (float*)(ws + 688896);
  float* bias2 = (float*)(ws + 689664);

  PrepArgs A0 = {w[0], b[0], im[0], ia[0], wk[0], bk[0], Wp0, bias0, 256};
  PrepArgs A1 = {w[1], b[1], im[1], ia[1], wk[1], bk[1], Wp1, bias1, 512};
  PrepArgs A2 = {w[2], b[2], im[2], ia[2], wk[2], bk[2], Wp2, bias2, 1024};
  prep_kernel<<<dim3(176, 3), 64, 0, stream>>>(A0, A1, A2);

  main_kernel<<<2100, 256, 0, stream>>>(f[0], f[1], f[2], Wp0, Wp1, Wp2, bias0, bias1, bias2,
                                        (float*)d_out);
}